// Round 1
// baseline (775.636 us; speedup 1.0000x reference)
//
#include <hip/hip_runtime.h>
#include <math.h>

// Problem constants (fixed by the reference)
//   B=2048 rows, L=64 lookback, N=1024 nodes
//   E=32 week emb, SE=16 stop emb, F=8 features, S=20 stops/row
//   N_SHARED=56, conv width NF=59
#define BLOCK 256

__global__ __launch_bounds__(BLOCK, 2) void markov_fused(
    const float* __restrict__ x,          // [B, L, N]
    const float* __restrict__ x_dist,     // [N]
    const float* __restrict__ x_features, // [B, F]
    const float* __restrict__ x_markov,   // [B, N]
    const int*   __restrict__ stops,      // [B, S]
    const int*   __restrict__ x_week,     // [B]
    const int*   __restrict__ x_mask,     // [B, N]
    const float* __restrict__ stop_emb,   // [N, SE]
    const float* __restrict__ week_emb,   // [NW, E]
    const float* __restrict__ conv_w,     // [N, NF]
    const float* __restrict__ conv_b,     // [N]
    const float* __restrict__ fc1_w,      // [L]
    const float* __restrict__ fc1_b,      // scalar
    float* __restrict__ out)              // [B, N]
{
    constexpr int L = 64, N = 1024, E = 32, SE = 16, F = 8, S = 20;
    constexpr int NSH = 56;   // E + F + SE
    constexpr int NF  = 59;   // NSH + 3
    constexpr int NPT = N / BLOCK;  // 4 columns per thread
    constexpr int NWAVE = BLOCK / 64;

    __shared__ float sh_shared[NSH];
    __shared__ float sh_fc1[L];
    __shared__ float red_max[NWAVE];
    __shared__ float red_sum[NWAVE];

    const int b = blockIdx.x;
    const int t = threadIdx.x;

    // ---- stage fc1 weights + the 56 node-independent "shared" features ----
    if (t < L) sh_fc1[t] = fc1_w[t];
    if (t < E) {
        sh_shared[t] = week_emb[x_week[b] * E + t];
    } else if (t < E + F) {
        sh_shared[t] = x_features[b * F + (t - E)];
    } else if (t < NSH) {
        int j = t - (E + F);
        float s = 0.f;
        #pragma unroll
        for (int k = 0; k < S; ++k)
            s += stop_emb[stops[b * S + k] * SE + j];
        sh_shared[t] = s;
    }
    __syncthreads();

    // ---- einsum over lookback: acc[n] = sum_l fc1_w[l] * x[b,l,n] ----
    // thread t owns columns 4t .. 4t+3 -> coalesced float4 loads
    const float4* xb = (const float4*)(x + (size_t)b * L * N);
    float4 acc = make_float4(0.f, 0.f, 0.f, 0.f);
    #pragma unroll 8
    for (int l = 0; l < L; ++l) {
        float  w = sh_fc1[l];
        float4 v = xb[l * (N / 4) + t];
        acc.x = fmaf(w, v.x, acc.x);
        acc.y = fmaf(w, v.y, acc.y);
        acc.z = fmaf(w, v.z, acc.z);
        acc.w = fmaf(w, v.w, acc.w);
    }
    const float bias = fc1_b[0];
    float o0 = acc.x + bias, o1 = acc.y + bias, o2 = acc.z + bias, o3 = acc.w + bias;

    // ---- logits for this thread's 4 columns ----
    float lg[NPT];
    float lmax = -INFINITY;
    const float* mkrow = x_markov + (size_t)b * N;
    #pragma unroll
    for (int i = 0; i < NPT; ++i) {
        const int n = 4 * t + i;
        const float* w = conv_w + (size_t)n * NF;
        float dot = 0.f;
        #pragma unroll
        for (int j = 0; j < NSH; ++j)
            dot = fmaf(sh_shared[j], w[j], dot);
        float o = (i == 0) ? o0 : (i == 1) ? o1 : (i == 2) ? o2 : o3;
        float v = dot
                + o          * w[NSH]
                + x_dist[n]  * w[NSH + 1]
                + mkrow[n]   * w[NSH + 2]
                + conv_b[n];
        lg[i] = v;
        lmax = fmaxf(lmax, v);
    }

    // ---- block-wide max ----
    #pragma unroll
    for (int off = 32; off > 0; off >>= 1)
        lmax = fmaxf(lmax, __shfl_down(lmax, off, 64));
    if ((t & 63) == 0) red_max[t >> 6] = lmax;
    __syncthreads();
    float m = red_max[0];
    #pragma unroll
    for (int i = 1; i < NWAVE; ++i) m = fmaxf(m, red_max[i]);

    // ---- block-wide sum of exp(logit - m) ----
    float se = 0.f;
    #pragma unroll
    for (int i = 0; i < NPT; ++i)
        se += expf(lg[i] - m);
    #pragma unroll
    for (int off = 32; off > 0; off >>= 1)
        se += __shfl_down(se, off, 64);
    if ((t & 63) == 0) red_sum[t >> 6] = se;
    __syncthreads();
    float Z = 0.f;
    #pragma unroll
    for (int i = 0; i < NWAVE; ++i) Z += red_sum[i];
    const float logZ = m + logf(Z);

    // ---- masked log-softmax, coalesced float4 store ----
    const int* mask = x_mask + (size_t)b * N;
    float4 res;
    res.x = mask[4 * t + 0] ? -1e8f : (lg[0] - logZ);
    res.y = mask[4 * t + 1] ? -1e8f : (lg[1] - logZ);
    res.z = mask[4 * t + 2] ? -1e8f : (lg[2] - logZ);
    res.w = mask[4 * t + 3] ? -1e8f : (lg[3] - logZ);
    ((float4*)(out + (size_t)b * N))[t] = res;
}

extern "C" void kernel_launch(void* const* d_in, const int* in_sizes, int n_in,
                              void* d_out, int out_size, void* d_ws, size_t ws_size,
                              hipStream_t stream) {
    const float* x          = (const float*)d_in[0];
    const float* x_dist     = (const float*)d_in[1];
    const float* x_features = (const float*)d_in[2];
    const float* x_markov   = (const float*)d_in[3];
    const int*   stops      = (const int*)  d_in[4];
    const int*   x_week     = (const int*)  d_in[5];
    const int*   x_mask     = (const int*)  d_in[6];
    const float* stop_emb   = (const float*)d_in[7];
    const float* week_emb   = (const float*)d_in[8];
    const float* conv_w     = (const float*)d_in[9];
    const float* conv_b     = (const float*)d_in[10];
    const float* fc1_w      = (const float*)d_in[11];
    const float* fc1_b      = (const float*)d_in[12];
    float* out = (float*)d_out;

    const int B = in_sizes[5];  // x_week has B elements
    markov_fused<<<B, BLOCK, 0, stream>>>(
        x, x_dist, x_features, x_markov, stops, x_week, x_mask,
        stop_emb, week_emb, conv_w, conv_b, fc1_w, fc1_b, out);
}

// Round 2
// 724.207 us; speedup vs baseline: 1.0710x; 1.0710x over previous
//
#include <hip/hip_runtime.h>
#include <math.h>

// Constants fixed by the reference:
// B=2048, L=64, N=1024, E=32, SE=16, F=8, NW=7, S=20, NSH=56, NF=59
#define BLOCK 256

constexpr int L = 64, N = 1024, E = 32, SE = 16, F = 8, S = 20;
constexpr int NSH = 56;
constexpr int NF  = 59;

// ---------------------------------------------------------------------------
// Kernel 1: per-row shared feature vector [B,56] = [week_emb | features | stop_emb_sum]
// ---------------------------------------------------------------------------
__global__ void compute_shared(const float* __restrict__ x_features,
                               const int*   __restrict__ stops,
                               const int*   __restrict__ x_week,
                               const float* __restrict__ stop_emb,
                               const float* __restrict__ week_emb,
                               float* __restrict__ sh_out)   // [B, 56]
{
    const int b = blockIdx.x;
    const int t = threadIdx.x;   // 64 threads
    if (t < E) {
        sh_out[b * NSH + t] = week_emb[x_week[b] * E + t];
    } else if (t < E + F) {
        sh_out[b * NSH + t] = x_features[b * F + (t - E)];
    } else if (t < NSH) {
        const int j = t - (E + F);
        float s = 0.f;
        #pragma unroll
        for (int k = 0; k < S; ++k)
            s += stop_emb[stops[b * S + k] * SE + j];
        sh_out[b * NSH + t] = s;
    }
}

// ---------------------------------------------------------------------------
// Kernel 2: unpack the conv kernel's 3 tail columns into coalesced arrays
// ---------------------------------------------------------------------------
__global__ void pack_w(const float* __restrict__ conv_w,
                       const float* __restrict__ x_dist,
                       const float* __restrict__ conv_b,
                       float* __restrict__ w56,       // [N]
                       float* __restrict__ w58,       // [N]
                       float* __restrict__ colconst)  // [N]
{
    const int n = blockIdx.x * blockDim.x + threadIdx.x;
    if (n < N) {
        const float* w = conv_w + (size_t)n * NF;
        w56[n] = w[NSH];
        w58[n] = w[NSH + 2];
        colconst[n] = x_dist[n] * w[NSH + 1] + conv_b[n];
    }
}

// ---------------------------------------------------------------------------
// Kernel 3: static[b,n] = shared[b,:] . conv_w[n,:56] + colconst[n]
// LDS-tiled 64x64 GEMM, K=56 in one shot. grid = (N/64, B/64), block = 256.
// ---------------------------------------------------------------------------
__global__ __launch_bounds__(BLOCK, 2) void gemm_static(
    const float* __restrict__ shf,       // [B, 56]
    const float* __restrict__ conv_w,    // [N, 59]
    const float* __restrict__ colconst,  // [N]
    float* __restrict__ statc)           // [B, N]
{
    __shared__ float Ash[64][NSH + 1];
    __shared__ float Bsh[64][NSH + 1];

    const int n0 = blockIdx.x * 64;
    const int b0 = blockIdx.y * 64;
    const int t  = threadIdx.x;

    for (int idx = t; idx < 64 * NSH; idx += BLOCK) {
        const int r = idx / NSH, c = idx % NSH;
        Ash[r][c] = shf[(size_t)(b0 + r) * NSH + c];
        Bsh[r][c] = conv_w[(size_t)(n0 + r) * NF + c];
    }
    __syncthreads();

    const int tx = t & 15, ty = t >> 4;
    float acc[4][4];
    #pragma unroll
    for (int i = 0; i < 4; ++i)
        #pragma unroll
        for (int k = 0; k < 4; ++k) acc[i][k] = 0.f;

    #pragma unroll 8
    for (int j = 0; j < NSH; ++j) {
        float a[4], bb[4];
        #pragma unroll
        for (int i = 0; i < 4; ++i) a[i]  = Ash[ty * 4 + i][j];
        #pragma unroll
        for (int i = 0; i < 4; ++i) bb[i] = Bsh[tx * 4 + i][j];
        #pragma unroll
        for (int i = 0; i < 4; ++i)
            #pragma unroll
            for (int k = 0; k < 4; ++k)
                acc[i][k] = fmaf(a[i], bb[k], acc[i][k]);
    }

    const float4 cc = *(const float4*)&colconst[n0 + tx * 4];
    #pragma unroll
    for (int i = 0; i < 4; ++i) {
        float4 r;
        r.x = acc[i][0] + cc.x;
        r.y = acc[i][1] + cc.y;
        r.z = acc[i][2] + cc.z;
        r.w = acc[i][3] + cc.w;
        *(float4*)&statc[(size_t)(b0 + ty * 4 + i) * N + n0 + tx * 4] = r;
    }
}

// ---------------------------------------------------------------------------
// Kernel 4 (hot): einsum over L + combine + log-softmax + mask.
// One block per row; thread t owns cols 4t..4t+3; all streams float4-coalesced.
// ---------------------------------------------------------------------------
__global__ __launch_bounds__(BLOCK, 4) void markov_main(
    const float* __restrict__ x,        // [B, L, N]
    const float* __restrict__ statc,    // [B, N]
    const float* __restrict__ w56,      // [N]
    const float* __restrict__ w58,      // [N]
    const float* __restrict__ x_markov, // [B, N]
    const int*   __restrict__ x_mask,   // [B, N]
    const float* __restrict__ fc1_w,    // [L]
    const float* __restrict__ fc1_b,    // scalar
    float* __restrict__ out)            // [B, N]
{
    constexpr int NWAVE = BLOCK / 64;
    __shared__ float sh_fc1[L];
    __shared__ float red_max[NWAVE];
    __shared__ float red_sum[NWAVE];

    const int b = blockIdx.x;
    const int t = threadIdx.x;

    if (t < L) sh_fc1[t] = fc1_w[t];
    __syncthreads();

    // einsum: acc[n] = sum_l fc1_w[l] * x[b,l,n]
    const float4* xb = (const float4*)(x + (size_t)b * L * N);
    float4 acc = make_float4(0.f, 0.f, 0.f, 0.f);
    #pragma unroll 16
    for (int l = 0; l < L; ++l) {
        const float  w = sh_fc1[l];
        const float4 v = xb[l * (N / 4) + t];
        acc.x = fmaf(w, v.x, acc.x);
        acc.y = fmaf(w, v.y, acc.y);
        acc.z = fmaf(w, v.z, acc.z);
        acc.w = fmaf(w, v.w, acc.w);
    }
    const float bias = fc1_b[0];

    const float4 st = ((const float4*)(statc + (size_t)b * N))[t];
    const float4 wa = ((const float4*)w56)[t];
    const float4 wc = ((const float4*)w58)[t];
    const float4 mk = ((const float4*)(x_markov + (size_t)b * N))[t];

    float lg[4];
    lg[0] = st.x + (acc.x + bias) * wa.x + mk.x * wc.x;
    lg[1] = st.y + (acc.y + bias) * wa.y + mk.y * wc.y;
    lg[2] = st.z + (acc.z + bias) * wa.z + mk.z * wc.z;
    lg[3] = st.w + (acc.w + bias) * wa.w + mk.w * wc.w;

    float lmax = fmaxf(fmaxf(lg[0], lg[1]), fmaxf(lg[2], lg[3]));
    #pragma unroll
    for (int off = 32; off > 0; off >>= 1)
        lmax = fmaxf(lmax, __shfl_down(lmax, off, 64));
    if ((t & 63) == 0) red_max[t >> 6] = lmax;
    __syncthreads();
    float m = red_max[0];
    #pragma unroll
    for (int i = 1; i < NWAVE; ++i) m = fmaxf(m, red_max[i]);

    float se = 0.f;
    #pragma unroll
    for (int i = 0; i < 4; ++i) se += expf(lg[i] - m);
    #pragma unroll
    for (int off = 32; off > 0; off >>= 1)
        se += __shfl_down(se, off, 64);
    if ((t & 63) == 0) red_sum[t >> 6] = se;
    __syncthreads();
    float Z = 0.f;
    #pragma unroll
    for (int i = 0; i < NWAVE; ++i) Z += red_sum[i];
    const float logZ = m + logf(Z);

    const int4 mask = ((const int4*)(x_mask + (size_t)b * N))[t];
    float4 res;
    res.x = mask.x ? -1e8f : (lg[0] - logZ);
    res.y = mask.y ? -1e8f : (lg[1] - logZ);
    res.z = mask.z ? -1e8f : (lg[2] - logZ);
    res.w = mask.w ? -1e8f : (lg[3] - logZ);
    ((float4*)(out + (size_t)b * N))[t] = res;
}

// ---------------------------------------------------------------------------
extern "C" void kernel_launch(void* const* d_in, const int* in_sizes, int n_in,
                              void* d_out, int out_size, void* d_ws, size_t ws_size,
                              hipStream_t stream) {
    const float* x          = (const float*)d_in[0];
    const float* x_dist     = (const float*)d_in[1];
    const float* x_features = (const float*)d_in[2];
    const float* x_markov   = (const float*)d_in[3];
    const int*   stops      = (const int*)  d_in[4];
    const int*   x_week     = (const int*)  d_in[5];
    const int*   x_mask     = (const int*)  d_in[6];
    const float* stop_emb   = (const float*)d_in[7];
    const float* week_emb   = (const float*)d_in[8];
    const float* conv_w     = (const float*)d_in[9];
    const float* conv_b     = (const float*)d_in[10];
    const float* fc1_w      = (const float*)d_in[11];
    const float* fc1_b      = (const float*)d_in[12];
    float* out = (float*)d_out;

    const int B = in_sizes[5];  // x_week has B elements

    // workspace layout (256-B aligned)
    char* ws = (char*)d_ws;
    float* sh_f     = (float*)(ws);                          // B*56
    float* w56      = (float*)(ws + ((size_t)B * NSH * 4 + 255) / 256 * 256);
    float* w58      = w56 + N;
    float* colconst = w58 + N;
    float* statc    = (float*)((char*)colconst + ((size_t)N * 4 + 255) / 256 * 256);  // B*N

    compute_shared<<<B, 64, 0, stream>>>(x_features, stops, x_week,
                                         stop_emb, week_emb, sh_f);
    pack_w<<<(N + 255) / 256, 256, 0, stream>>>(conv_w, x_dist, conv_b,
                                                w56, w58, colconst);
    dim3 ggrid(N / 64, B / 64);
    gemm_static<<<ggrid, BLOCK, 0, stream>>>(sh_f, conv_w, colconst, statc);
    markov_main<<<B, BLOCK, 0, stream>>>(x, statc, w56, w58, x_markov, x_mask,
                                         fc1_w, fc1_b, out);
}

// Round 3
// 704.835 us; speedup vs baseline: 1.1005x; 1.0275x over previous
//
#include <hip/hip_runtime.h>
#include <math.h>

// Constants fixed by the reference:
// B=2048, L=64, N=1024, E=32, SE=16, F=8, NW=7, S=20, NSH=56, NF=59
#define BLOCK 256

constexpr int L = 64, N = 1024, E = 32, SE = 16, F = 8, S = 20;
constexpr int NSH = 56;
constexpr int NF  = 59;

typedef float f4 __attribute__((ext_vector_type(4)));

// ---------------------------------------------------------------------------
// Kernel 1 (prep): blocks [0,B) build the per-row 56-vector
//                  blocks [B, B+N/64) unpack conv_w tail columns
// 64 threads per block.
// ---------------------------------------------------------------------------
__global__ void prep(const float* __restrict__ x_features,
                     const int*   __restrict__ stops,
                     const int*   __restrict__ x_week,
                     const float* __restrict__ stop_emb,
                     const float* __restrict__ week_emb,
                     const float* __restrict__ conv_w,
                     const float* __restrict__ x_dist,
                     const float* __restrict__ conv_b,
                     float* __restrict__ sh_out,    // [B, 56]
                     float* __restrict__ w56,       // [N]
                     float* __restrict__ w58,       // [N]
                     float* __restrict__ colconst,  // [N]
                     int B)
{
    const int blk = blockIdx.x;
    const int t = threadIdx.x;   // 64 threads
    if (blk < B) {
        const int b = blk;
        if (t < E) {
            sh_out[b * NSH + t] = week_emb[x_week[b] * E + t];
        } else if (t < E + F) {
            sh_out[b * NSH + t] = x_features[b * F + (t - E)];
        } else if (t < NSH) {
            const int j = t - (E + F);
            float s = 0.f;
            #pragma unroll
            for (int k = 0; k < S; ++k)
                s += stop_emb[stops[b * S + k] * SE + j];
            sh_out[b * NSH + t] = s;
        }
    } else {
        const int n = (blk - B) * 64 + t;
        if (n < N) {
            const float* w = conv_w + (size_t)n * NF;
            w56[n] = w[NSH];
            w58[n] = w[NSH + 2];
            colconst[n] = x_dist[n] * w[NSH + 1] + conv_b[n];
        }
    }
}

// ---------------------------------------------------------------------------
// Kernel 2: static[b,n] = shared[b,:] . conv_w[n,:56] + colconst[n]
// LDS-tiled 64x64 GEMM, K=56 in one shot. grid = (N/64, B/64), block = 256.
// ---------------------------------------------------------------------------
__global__ __launch_bounds__(BLOCK, 2) void gemm_static(
    const float* __restrict__ shf,       // [B, 56]
    const float* __restrict__ conv_w,    // [N, 59]
    const float* __restrict__ colconst,  // [N]
    float* __restrict__ statc)           // [B, N]
{
    __shared__ float Ash[64][NSH + 1];
    __shared__ float Bsh[64][NSH + 1];

    const int n0 = blockIdx.x * 64;
    const int b0 = blockIdx.y * 64;
    const int t  = threadIdx.x;

    for (int idx = t; idx < 64 * NSH; idx += BLOCK) {
        const int r = idx / NSH, c = idx % NSH;
        Ash[r][c] = shf[(size_t)(b0 + r) * NSH + c];
        Bsh[r][c] = conv_w[(size_t)(n0 + r) * NF + c];
    }
    __syncthreads();

    const int tx = t & 15, ty = t >> 4;
    float acc[4][4];
    #pragma unroll
    for (int i = 0; i < 4; ++i)
        #pragma unroll
        for (int k = 0; k < 4; ++k) acc[i][k] = 0.f;

    #pragma unroll 8
    for (int j = 0; j < NSH; ++j) {
        float a[4], bb[4];
        #pragma unroll
        for (int i = 0; i < 4; ++i) a[i]  = Ash[ty * 4 + i][j];
        #pragma unroll
        for (int i = 0; i < 4; ++i) bb[i] = Bsh[tx * 4 + i][j];
        #pragma unroll
        for (int i = 0; i < 4; ++i)
            #pragma unroll
            for (int k = 0; k < 4; ++k)
                acc[i][k] = fmaf(a[i], bb[k], acc[i][k]);
    }

    const float4 cc = *(const float4*)&colconst[n0 + tx * 4];
    #pragma unroll
    for (int i = 0; i < 4; ++i) {
        float4 r;
        r.x = acc[i][0] + cc.x;
        r.y = acc[i][1] + cc.y;
        r.z = acc[i][2] + cc.z;
        r.w = acc[i][3] + cc.w;
        *(float4*)&statc[(size_t)(b0 + ty * 4 + i) * N + n0 + tx * 4] = r;
    }
}

// ---------------------------------------------------------------------------
// Kernel 3 (hot): einsum over L + combine + log-softmax + mask.
// One block per row; thread t owns cols 4t..4t+3.
// x is streamed with non-temporal loads (read-once, 2x LLC size) so the
// reused small arrays (statc/w56/w58/conv_w) stay cache-resident.
// ---------------------------------------------------------------------------
__global__ __launch_bounds__(BLOCK, 4) void markov_main(
    const float* __restrict__ x,        // [B, L, N]
    const float* __restrict__ statc,    // [B, N]
    const float* __restrict__ w56,      // [N]
    const float* __restrict__ w58,      // [N]
    const float* __restrict__ x_markov, // [B, N]
    const int*   __restrict__ x_mask,   // [B, N]
    const float* __restrict__ fc1_w,    // [L]
    const float* __restrict__ fc1_b,    // scalar
    float* __restrict__ out)            // [B, N]
{
    constexpr int NWAVE = BLOCK / 64;
    __shared__ float sh_fc1[L];
    __shared__ float red_max[NWAVE];
    __shared__ float red_sum[NWAVE];

    const int b = blockIdx.x;
    const int t = threadIdx.x;

    if (t < L) sh_fc1[t] = fc1_w[t];
    __syncthreads();

    // einsum: acc[n] = sum_l fc1_w[l] * x[b,l,n]   (nt float4 stream)
    const f4* xb = (const f4*)(x + (size_t)b * L * N);
    f4 acc = (f4)(0.f);
    #pragma unroll 16
    for (int l = 0; l < L; ++l) {
        const float w = sh_fc1[l];
        const f4 v = __builtin_nontemporal_load(&xb[l * (N / 4) + t]);
        acc[0] = fmaf(w, v[0], acc[0]);
        acc[1] = fmaf(w, v[1], acc[1]);
        acc[2] = fmaf(w, v[2], acc[2]);
        acc[3] = fmaf(w, v[3], acc[3]);
    }
    const float bias = fc1_b[0];

    const float4 st = ((const float4*)(statc + (size_t)b * N))[t];
    const float4 wa = ((const float4*)w56)[t];
    const float4 wc = ((const float4*)w58)[t];
    const float4 mk = ((const float4*)(x_markov + (size_t)b * N))[t];

    float lg[4];
    lg[0] = st.x + (acc[0] + bias) * wa.x + mk.x * wc.x;
    lg[1] = st.y + (acc[1] + bias) * wa.y + mk.y * wc.y;
    lg[2] = st.z + (acc[2] + bias) * wa.z + mk.z * wc.z;
    lg[3] = st.w + (acc[3] + bias) * wa.w + mk.w * wc.w;

    float lmax = fmaxf(fmaxf(lg[0], lg[1]), fmaxf(lg[2], lg[3]));
    #pragma unroll
    for (int off = 32; off > 0; off >>= 1)
        lmax = fmaxf(lmax, __shfl_down(lmax, off, 64));
    if ((t & 63) == 0) red_max[t >> 6] = lmax;
    __syncthreads();
    float m = red_max[0];
    #pragma unroll
    for (int i = 1; i < NWAVE; ++i) m = fmaxf(m, red_max[i]);

    float se = 0.f;
    #pragma unroll
    for (int i = 0; i < 4; ++i) se += __expf(lg[i] - m);
    #pragma unroll
    for (int off = 32; off > 0; off >>= 1)
        se += __shfl_down(se, off, 64);
    if ((t & 63) == 0) red_sum[t >> 6] = se;
    __syncthreads();
    float Z = 0.f;
    #pragma unroll
    for (int i = 0; i < NWAVE; ++i) Z += red_sum[i];
    const float logZ = m + __logf(Z);

    const int4 mask = ((const int4*)(x_mask + (size_t)b * N))[t];
    f4 res;
    res[0] = mask.x ? -1e8f : (lg[0] - logZ);
    res[1] = mask.y ? -1e8f : (lg[1] - logZ);
    res[2] = mask.z ? -1e8f : (lg[2] - logZ);
    res[3] = mask.w ? -1e8f : (lg[3] - logZ);
    __builtin_nontemporal_store(res, &((f4*)(out + (size_t)b * N))[t]);
}

// ---------------------------------------------------------------------------
extern "C" void kernel_launch(void* const* d_in, const int* in_sizes, int n_in,
                              void* d_out, int out_size, void* d_ws, size_t ws_size,
                              hipStream_t stream) {
    const float* x          = (const float*)d_in[0];
    const float* x_dist     = (const float*)d_in[1];
    const float* x_features = (const float*)d_in[2];
    const float* x_markov   = (const float*)d_in[3];
    const int*   stops      = (const int*)  d_in[4];
    const int*   x_week     = (const int*)  d_in[5];
    const int*   x_mask     = (const int*)  d_in[6];
    const float* stop_emb   = (const float*)d_in[7];
    const float* week_emb   = (const float*)d_in[8];
    const float* conv_w     = (const float*)d_in[9];
    const float* conv_b     = (const float*)d_in[10];
    const float* fc1_w      = (const float*)d_in[11];
    const float* fc1_b      = (const float*)d_in[12];
    float* out = (float*)d_out;

    const int B = in_sizes[5];  // x_week has B elements

    // workspace layout (256-B aligned)
    char* ws = (char*)d_ws;
    float* sh_f     = (float*)(ws);                          // B*56
    float* w56      = (float*)(ws + ((size_t)B * NSH * 4 + 255) / 256 * 256);
    float* w58      = w56 + N;
    float* colconst = w58 + N;
    float* statc    = (float*)((char*)colconst + ((size_t)N * 4 + 255) / 256 * 256);  // B*N

    prep<<<B + N / 64, 64, 0, stream>>>(x_features, stops, x_week,
                                        stop_emb, week_emb, conv_w, x_dist, conv_b,
                                        sh_f, w56, w58, colconst, B);
    dim3 ggrid(N / 64, B / 64);
    gemm_static<<<ggrid, BLOCK, 0, stream>>>(sh_f, conv_w, colconst, statc);
    markov_main<<<B, BLOCK, 0, stream>>>(x, statc, w56, w58, x_markov, x_mask,
                                         fc1_w, fc1_b, out);
}